// Round 1
// baseline (1115.079 us; speedup 1.0000x reference)
//
#include <hip/hip_runtime.h>

// VQ-VAE vector quantizer: B=32768, K=4096, D=256 (fp32)
// out = [quantized (B*D floats), vq_loss (1 float)]
//
// Pipeline:
//  k1: enorm[k] = ||E_k||^2  (fp64-accumulated, stored fp32)
//  k2: fused fp32 GEMM + per-row top-2 argmin over each K/2 chunk
//  k3: fp64 rescore of the <=4 candidates -> exact winner, gather E row to out,
//      accumulate fp64 loss partial per block
//  k4: reduce partials -> vq_loss = 1.25 * mean((x-q)^2)

#define B_N 32768
#define K_N 4096
#define D_N 256

#define BR 128     // rows per block tile
#define BC 256     // codes per k-tile
#define DT 32      // d-tile
#define KCHUNK 2048
#define NCHUNK 2

// workspace layout
static constexpr size_t TOP2_OFF  = 0;                                   // 32768*2*16 = 1 MB
static constexpr size_t ENORM_OFF = (size_t)B_N * NCHUNK * 16;           // +16 KB
static constexpr size_t PART_OFF  = ENORM_OFF + (size_t)K_N * 4;         // +4 KB (512 doubles)

__global__ void enorm_kernel(const float* __restrict__ E, float* __restrict__ enorm) {
    const int gtid = blockIdx.x * blockDim.x + threadIdx.x;
    const int wave = gtid >> 6;
    const int lane = threadIdx.x & 63;
    if (wave >= K_N) return;
    const float4 v = *reinterpret_cast<const float4*>(E + (size_t)wave * D_N + lane * 4);
    double s = (double)v.x * v.x + (double)v.y * v.y + (double)v.z * v.z + (double)v.w * v.w;
    #pragma unroll
    for (int o = 32; o; o >>= 1) s += __shfl_xor(s, o, 64);
    if (lane == 0) enorm[wave] = (float)s;
}

// 256 threads: tx = tid&15 (codes), ty = tid>>4 (rows)
// micro-tile: 8 rows (r = ty + 16*i) x 16 codes (c = tx + 16*j)
__launch_bounds__(256, 2)
__global__ void dist_top2_kernel(const float* __restrict__ X, const float* __restrict__ E,
                                 const float* __restrict__ enorm, float4* __restrict__ top2) {
    __shared__ float sm[BR * 33 + BC * 33];   // 50688 B
    float* Xs = sm;             // [BR][33]
    float* Es = sm + BR * 33;   // [BC][33]

    const int tid = threadIdx.x;
    const int tx = tid & 15, ty = tid >> 4;
    const int rb = blockIdx.x;          // row block 0..255
    const int chunk = blockIdx.y;       // 0..1
    const int k0 = chunk * KCHUNK;

    float v0[8], v1[8];
    int   i0[8], i1[8];
    #pragma unroll
    for (int i = 0; i < 8; ++i) { v0[i] = 3.4e38f; v1[i] = 3.4e38f; i0[i] = 0x7fffffff; i1[i] = 0x7fffffff; }

    for (int kt = 0; kt < KCHUNK; kt += BC) {
        const int kb = k0 + kt;
        float acc[8][16];
        #pragma unroll
        for (int i = 0; i < 8; ++i)
            #pragma unroll
            for (int j = 0; j < 16; ++j) acc[i][j] = 0.f;

        for (int dt = 0; dt < D_N; dt += DT) {
            __syncthreads();
            // stage X tile: 128x32 floats = 1024 float4, 4 per thread
            #pragma unroll
            for (int r = 0; r < 4; ++r) {
                int f = tid + 256 * r;          // 0..1023
                int row = f >> 3;               // 0..127
                int dg  = (f & 7) * 4;          // 0..28
                float4 xv = *reinterpret_cast<const float4*>(
                    X + ((size_t)(rb * BR + row)) * D_N + dt + dg);
                *reinterpret_cast<float4*>(Xs + row * 33 + dg) = xv;
            }
            // stage E tile: 256x32 floats = 2048 float4, 8 per thread
            #pragma unroll
            for (int r = 0; r < 8; ++r) {
                int f = tid + 256 * r;          // 0..2047
                int row = f >> 3;               // 0..255
                int dg  = (f & 7) * 4;
                float4 ev = *reinterpret_cast<const float4*>(
                    E + ((size_t)(kb + row)) * D_N + dt + dg);
                *reinterpret_cast<float4*>(Es + row * 33 + dg) = ev;
            }
            __syncthreads();

            #pragma unroll 4
            for (int d = 0; d < DT; ++d) {
                float xr[8], ec[16];
                #pragma unroll
                for (int i = 0; i < 8; ++i) xr[i] = Xs[(ty + 16 * i) * 33 + d];
                #pragma unroll
                for (int j = 0; j < 16; ++j) ec[j] = Es[(tx + 16 * j) * 33 + d];
                #pragma unroll
                for (int i = 0; i < 8; ++i)
                    #pragma unroll
                    for (int j = 0; j < 16; ++j)
                        acc[i][j] = fmaf(xr[i], ec[j], acc[i][j]);
            }
        }

        // min-update: d = ||e||^2 - 2*x.e  (row-constant ||x||^2 dropped)
        #pragma unroll
        for (int j = 0; j < 16; ++j) {
            const int idx = kb + tx + 16 * j;
            const float en = enorm[idx];
            #pragma unroll
            for (int i = 0; i < 8; ++i) {
                float v = fmaf(-2.f, acc[i][j], en);
                if (v < v0[i]) { v1[i] = v0[i]; i1[i] = i0[i]; v0[i] = v; i0[i] = idx; }
                else if (v < v1[i]) { v1[i] = v; i1[i] = idx; }
            }
        }
    }

    // cross-thread merge over the 16 tx owning the same rows
    __syncthreads();
    float2* M = reinterpret_cast<float2*>(sm);   // [128][32] (v, idx-bits) = 32 KB
    #pragma unroll
    for (int i = 0; i < 8; ++i) {
        int r = ty + 16 * i;
        M[r * 32 + tx * 2 + 0] = make_float2(v0[i], __int_as_float(i0[i]));
        M[r * 32 + tx * 2 + 1] = make_float2(v1[i], __int_as_float(i1[i]));
    }
    __syncthreads();
    if (tid < BR) {
        float bv0 = 3.4e38f, bv1 = 3.4e38f;
        int   bi0 = 0x7fffffff, bi1 = 0x7fffffff;
        for (int s = 0; s < 32; ++s) {
            float2 e = M[tid * 32 + s];
            float v = e.x; int idx = __float_as_int(e.y);
            if (v < bv0 || (v == bv0 && idx < bi0)) { bv1 = bv0; bi1 = bi0; bv0 = v; bi0 = idx; }
            else if (v < bv1 || (v == bv1 && idx < bi1)) { bv1 = v; bi1 = idx; }
        }
        int row = rb * BR + tid;
        top2[(size_t)row * NCHUNK + chunk] =
            make_float4(bv0, __int_as_float(bi0), bv1, __int_as_float(bi1));
    }
}

__global__ void rescore_kernel(const float* __restrict__ X, const float* __restrict__ E,
                               const float4* __restrict__ top2, float* __restrict__ out,
                               double* __restrict__ partials) {
    const int lane = threadIdx.x & 63;
    const int wid  = (blockIdx.x * blockDim.x + threadIdx.x) >> 6;
    const int nw   = (gridDim.x * blockDim.x) >> 6;
    double wloc = 0.0;

    for (int row = wid; row < B_N; row += nw) {
        float4 t0 = top2[(size_t)row * NCHUNK + 0];
        float4 t1 = top2[(size_t)row * NCHUNK + 1];
        int cand[4] = { __float_as_int(t0.y), __float_as_int(t0.w),
                        __float_as_int(t1.y), __float_as_int(t1.w) };
        const float4 xv = *reinterpret_cast<const float4*>(X + (size_t)row * D_N + lane * 4);

        double bestd = 1e300; int besti = 0x7fffffff;
        float4 beste = make_float4(0.f, 0.f, 0.f, 0.f);
        #pragma unroll
        for (int c = 0; c < 4; ++c) {
            const int k = cand[c];
            const float4 ev = *reinterpret_cast<const float4*>(E + (size_t)k * D_N + lane * 4);
            double dx = (double)xv.x - (double)ev.x;
            double dy = (double)xv.y - (double)ev.y;
            double dz = (double)xv.z - (double)ev.z;
            double dw = (double)xv.w - (double)ev.w;
            double s = dx * dx + dy * dy + dz * dz + dw * dw;
            #pragma unroll
            for (int o = 32; o; o >>= 1) s += __shfl_xor(s, o, 64);
            if (s < bestd || (s == bestd && k < besti)) { bestd = s; besti = k; beste = ev; }
        }
        *reinterpret_cast<float4*>(out + (size_t)row * D_N + lane * 4) = beste;
        wloc += bestd;
    }

    __shared__ double bsum[8];
    const int widx = threadIdx.x >> 6;
    if (lane == 0) bsum[widx] = wloc;
    __syncthreads();
    if (threadIdx.x == 0) {
        double s = 0.0;
        for (int w = 0; w < (int)(blockDim.x >> 6); ++w) s += bsum[w];
        partials[blockIdx.x] = s;
    }
}

__global__ void finalize_kernel(const double* __restrict__ partials, int n,
                                float* __restrict__ loss_out) {
    __shared__ double sm[256];
    double s = 0.0;
    for (int i = threadIdx.x; i < n; i += 256) s += partials[i];
    sm[threadIdx.x] = s;
    __syncthreads();
    for (int st = 128; st; st >>= 1) {
        if (threadIdx.x < st) sm[threadIdx.x] += sm[threadIdx.x + st];
        __syncthreads();
    }
    if (threadIdx.x == 0)
        *loss_out = (float)(1.25 * sm[0] / (double)((size_t)B_N * D_N));
}

extern "C" void kernel_launch(void* const* d_in, const int* in_sizes, int n_in,
                              void* d_out, int out_size, void* d_ws, size_t ws_size,
                              hipStream_t stream) {
    const float* X = (const float*)d_in[0];   // [B, D]
    const float* E = (const float*)d_in[1];   // [K, D]
    float* out = (float*)d_out;               // [B*D] quantized, then [1] loss
    char* ws = (char*)d_ws;

    float4* top2     = (float4*)(ws + TOP2_OFF);
    float*  enorm    = (float*)(ws + ENORM_OFF);
    double* partials = (double*)(ws + PART_OFF);

    enorm_kernel<<<K_N / 4, 256, 0, stream>>>(E, enorm);
    dist_top2_kernel<<<dim3(B_N / BR, NCHUNK), 256, 0, stream>>>(X, E, enorm, top2);
    rescore_kernel<<<512, 256, 0, stream>>>(X, E, top2, out, partials);
    finalize_kernel<<<1, 256, 0, stream>>>(partials, 512, out + (size_t)B_N * D_N);
}

// Round 2
// 289.672 us; speedup vs baseline: 3.8494x; 3.8494x over previous
//
#include <hip/hip_runtime.h>
#include <hip/hip_bf16.h>

// VQ-VAE vector quantizer: B=32768, K=4096, D=256 (fp32)
// out = [quantized (B*D floats), vq_loss (1 float)]
//
// Pipeline:
//  k0: xconv  — split X into bf16 hi/lo, stored PRE-SWIZZLED in d_out (32 MiB,
//               overwritten later by rescore) in [rb][dstep][term][frag][lane][8] order
//               so global_load_lds stages it linearly with conflict-free frag reads.
//  k1: en2    — en2[k] = 0.5*||E_k||^2 (fp64-accumulated)
//  k2: dist   — MFMA bf16x3 GEMM (S = Xh*Eh + Xl*Eh + Xh*El), val = en2 - S,
//               per-row top-2 per 2048-code chunk (argmin-equivalent)
//  k3: rescore— fp64 rescore of the 4 candidates -> exact winner, gather, loss partials
//  k4: finalize loss = 1.25 * mean((x-q)^2)

#define B_N 32768
#define K_N 4096
#define D_N 256
#define NCHUNK 2
#define KCHUNK 2048

typedef short bf16x8 __attribute__((ext_vector_type(8)));
typedef float f32x4 __attribute__((ext_vector_type(4)));
typedef unsigned int uint4v __attribute__((ext_vector_type(4)));
typedef unsigned short u16;

// workspace layout (proven footprint ~1.07MB)
static constexpr size_t TOP2_OFF = 0;                                 // 32768*2*16 = 1 MB
static constexpr size_t EN2_OFF  = (size_t)B_N * NCHUNK * 16;         // +16 KB
static constexpr size_t PART_OFF = EN2_OFF + (size_t)K_N * 4;         // +4 KB

__device__ __forceinline__ u16 f2bf(float f) {
    unsigned h = __builtin_bit_cast(unsigned short, __float2bfloat16(f));
    return (u16)h;
}

__device__ __forceinline__ void gload_lds16(const void* g, void* l) {
    __builtin_amdgcn_global_load_lds(
        (const __attribute__((address_space(1))) void*)g,
        (__attribute__((address_space(3))) void*)l, 16, 0, 0);
}

__device__ __forceinline__ void top2_merge(float& v0, int& i0, float& v1, int& i1,
                                           float ov0, int oi0, float ov1, int oi1) {
    bool bf_ = (ov0 < v0) || (ov0 == v0 && oi0 < i0);
    float w0v = bf_ ? ov0 : v0;  int w0i = bf_ ? oi0 : i0;
    float lv  = bf_ ? v0  : ov0; int li  = bf_ ? i0  : oi0;
    float cv  = bf_ ? ov1 : v1;  int ci  = bf_ ? oi1 : i1;
    bool tl = (lv < cv) || (lv == cv && li < ci);
    v0 = w0v; i0 = w0i;
    v1 = tl ? lv : cv; i1 = tl ? li : ci;
}

// ---------- k0: X hi/lo split into swizzled global layout ----------
// layout (ushort units): region(rb,dstep,term) = ((rb*4+dstep)*2+term)*8192
// within region: ((rf*2+ks)*64 + lane)*8 + j
// where row = rb*128 + rf*16 + (lane&15); d = dstep*64 + ks*32 + (lane>>4)*8 + j
__global__ void xconv_kernel(const float* __restrict__ X, u16* __restrict__ Xsw) {
    const int gid = blockIdx.x * 256 + threadIdx.x;     // B_N*32 threads
    const int row = gid >> 5;
    const int d0  = (gid & 31) << 3;
    const float4 a = *reinterpret_cast<const float4*>(X + (size_t)row * D_N + d0);
    const float4 b = *reinterpret_cast<const float4*>(X + (size_t)row * D_N + d0 + 4);
    float f[8] = {a.x, a.y, a.z, a.w, b.x, b.y, b.z, b.w};
    unsigned hi[8], lo[8];
    #pragma unroll
    for (int j = 0; j < 8; ++j) {
        hi[j] = f2bf(f[j]);
        float hf = __uint_as_float(hi[j] << 16);
        lo[j] = f2bf(f[j] - hf);
    }
    const int rb = row >> 7, r = row & 127, rf = r >> 4, llo = r & 15;
    const int dstep = d0 >> 6, dd = d0 & 63, ks = dd >> 5, lhi = (dd & 31) >> 3;
    const int lane = (lhi << 4) | llo;
    size_t base = (size_t)(rb * 4 + dstep) * 16384 + (size_t)((rf * 2 + ks) * 64 + lane) * 8;
    uint4v hv, lv;
    hv.x = hi[0] | (hi[1] << 16); hv.y = hi[2] | (hi[3] << 16);
    hv.z = hi[4] | (hi[5] << 16); hv.w = hi[6] | (hi[7] << 16);
    lv.x = lo[0] | (lo[1] << 16); lv.y = lo[2] | (lo[3] << 16);
    lv.z = lo[4] | (lo[5] << 16); lv.w = lo[6] | (lo[7] << 16);
    *reinterpret_cast<uint4v*>(Xsw + base) = hv;           // term 0 (hi)
    *reinterpret_cast<uint4v*>(Xsw + base + 8192) = lv;    // term 1 (lo)
}

// ---------- k1: en2 = 0.5*||e||^2 ----------
__global__ void en2_kernel(const float* __restrict__ E, float* __restrict__ en2) {
    const int gtid = blockIdx.x * blockDim.x + threadIdx.x;
    const int wave = gtid >> 6;
    const int lane = threadIdx.x & 63;
    if (wave >= K_N) return;
    const float4 v = *reinterpret_cast<const float4*>(E + (size_t)wave * D_N + lane * 4);
    double s = (double)v.x * v.x + (double)v.y * v.y + (double)v.z * v.z + (double)v.w * v.w;
    #pragma unroll
    for (int o = 32; o; o >>= 1) s += __shfl_xor(s, o, 64);
    if (lane == 0) en2[wave] = (float)(0.5 * s);
}

// ---------- k2: fused bf16x3 MFMA GEMM + top-2 argmin ----------
// block: 256 thr = 4 waves (2x2), tile 128 rows x 128 codes, K inner chunk loop.
__launch_bounds__(256, 2)
__global__ void dist_kernel(const u16* __restrict__ Xsw, const float* __restrict__ E,
                            const float* __restrict__ en2, float4* __restrict__ top2) {
    __shared__ __align__(16) u16 lds[32768];   // 64KB: Xs [0,16384), Es [16384,32768) ushorts
    const int tid  = threadIdx.x;
    const int lane = tid & 63;
    const int wid  = tid >> 6;
    const int wr   = wid >> 1, wc = wid & 1;
    const int llo  = lane & 15, lhi = lane >> 4;
    const int rb = blockIdx.x;
    const int chunk = blockIdx.y;

    float tv0[16], tv1[16];
    int   tpk[16];                       // (i1<<16)|i0
    #pragma unroll
    for (int s = 0; s < 16; ++s) { tv0[s] = 3.4e38f; tv1[s] = 3.4e38f; tpk[s] = -1; }

    const bf16x8* ldsv = reinterpret_cast<const bf16x8*>(lds);
    const char* xbase = reinterpret_cast<const char*>(Xsw) + (size_t)rb * 131072;

    for (int cb = 0; cb < KCHUNK / 128; ++cb) {
        const int codebase = chunk * KCHUNK + cb * 128;
        f32x4 acc[4][4];
        #pragma unroll
        for (int i = 0; i < 4; ++i)
            #pragma unroll
            for (int j = 0; j < 4; ++j)
                acc[i][j] = (f32x4){0.f, 0.f, 0.f, 0.f};
        float en2v[4];
        #pragma unroll
        for (int j = 0; j < 4; ++j) en2v[j] = en2[codebase + (wc * 4 + j) * 16 + llo];

        for (int dstep = 0; dstep < 4; ++dstep) {
            __syncthreads();                    // LDS free (prev compute done)
            // stage X hi+lo tile (32KB) via global_load_lds, linear
            const char* xsrc = xbase + (size_t)dstep * 32768;
            #pragma unroll
            for (int it = 0; it < 8; ++it) {
                gload_lds16(xsrc + it * 4096 + wid * 1024 + lane * 16,
                            reinterpret_cast<char*>(lds) + it * 4096 + wid * 1024);
            }
            // stage E tile: fp32 -> bf16 hi/lo in-register -> ds_write (lane-linear)
            #pragma unroll
            for (int cfi = 0; cfi < 2; ++cfi) {
                const int cf = wid * 2 + cfi;
                const int code = codebase + cf * 16 + llo;
                #pragma unroll
                for (int ks = 0; ks < 2; ++ks) {
                    const int d = dstep * 64 + ks * 32 + lhi * 8;
                    const float* ep = E + (size_t)code * D_N + d;
                    const float4 ea = *reinterpret_cast<const float4*>(ep);
                    const float4 eb = *reinterpret_cast<const float4*>(ep + 4);
                    float f[8] = {ea.x, ea.y, ea.z, ea.w, eb.x, eb.y, eb.z, eb.w};
                    unsigned h[8], l[8];
                    #pragma unroll
                    for (int j = 0; j < 8; ++j) {
                        h[j] = f2bf(f[j]);
                        float hf = __uint_as_float(h[j] << 16);
                        l[j] = f2bf(f[j] - hf);
                    }
                    uint4v hv, lv;
                    hv.x = h[0] | (h[1] << 16); hv.y = h[2] | (h[3] << 16);
                    hv.z = h[4] | (h[5] << 16); hv.w = h[6] | (h[7] << 16);
                    lv.x = l[0] | (l[1] << 16); lv.y = l[2] | (l[3] << 16);
                    lv.z = l[4] | (l[5] << 16); lv.w = l[6] | (l[7] << 16);
                    const int uoff = 16384 + ((cf * 2 + ks) * 64 + lane) * 8;
                    *reinterpret_cast<uint4v*>(lds + uoff) = hv;           // Eh
                    *reinterpret_cast<uint4v*>(lds + uoff + 8192) = lv;    // El
                }
            }
            __syncthreads();                    // drains vmcnt+lgkmcnt

            #pragma unroll
            for (int ks = 0; ks < 2; ++ks) {
                bf16x8 ah[4], bh[4], al[4], bl[4];
                #pragma unroll
                for (int i = 0; i < 4; ++i) ah[i] = ldsv[((wr * 4 + i) * 2 + ks) * 64 + lane];
                #pragma unroll
                for (int j = 0; j < 4; ++j) bh[j] = ldsv[2048 + ((wc * 4 + j) * 2 + ks) * 64 + lane];
                #pragma unroll
                for (int i = 0; i < 4; ++i)
                    #pragma unroll
                    for (int j = 0; j < 4; ++j)
                        acc[i][j] = __builtin_amdgcn_mfma_f32_16x16x32_bf16(ah[i], bh[j], acc[i][j], 0, 0, 0);
                #pragma unroll
                for (int i = 0; i < 4; ++i) al[i] = ldsv[1024 + ((wr * 4 + i) * 2 + ks) * 64 + lane];
                #pragma unroll
                for (int i = 0; i < 4; ++i)
                    #pragma unroll
                    for (int j = 0; j < 4; ++j)
                        acc[i][j] = __builtin_amdgcn_mfma_f32_16x16x32_bf16(al[i], bh[j], acc[i][j], 0, 0, 0);
                #pragma unroll
                for (int j = 0; j < 4; ++j) bl[j] = ldsv[3072 + ((wc * 4 + j) * 2 + ks) * 64 + lane];
                #pragma unroll
                for (int i = 0; i < 4; ++i)
                    #pragma unroll
                    for (int j = 0; j < 4; ++j)
                        acc[i][j] = __builtin_amdgcn_mfma_f32_16x16x32_bf16(ah[i], bl[j], acc[i][j], 0, 0, 0);
            }
        }

        // epilogue: val = en2 - S, top-2 update (packed idx)
        #pragma unroll
        for (int j = 0; j < 4; ++j) {
            const int idx = codebase + (wc * 4 + j) * 16 + llo;
            const float en = en2v[j];
            #pragma unroll
            for (int i = 0; i < 4; ++i) {
                #pragma unroll
                for (int r = 0; r < 4; ++r) {
                    const float v = en - acc[i][j][r];
                    const int s = i * 4 + r;
                    const bool c0 = v < tv0[s];
                    const bool c1 = v < tv1[s];
                    const int pk = tpk[s];
                    const int pkA = (pk << 16) | idx;
                    const int pkB = (idx << 16) | (pk & 0xffff);
                    tv1[s] = c0 ? tv0[s] : (c1 ? v : tv1[s]);
                    tv0[s] = c0 ? v : tv0[s];
                    tpk[s] = c0 ? pkA : (c1 ? pkB : pk);
                }
            }
        }
    }

    // cross-lane butterfly merge over the 16 column-lanes
    #pragma unroll
    for (int m = 1; m <= 8; m <<= 1) {
        #pragma unroll
        for (int s = 0; s < 16; ++s) {
            float ov0 = __shfl_xor(tv0[s], m, 64);
            float ov1 = __shfl_xor(tv1[s], m, 64);
            int   opk = __shfl_xor(tpk[s], m, 64);
            float v0 = tv0[s], v1 = tv1[s];
            int i0 = tpk[s] & 0xffff, i1 = (tpk[s] >> 16) & 0xffff;
            top2_merge(v0, i0, v1, i1, ov0, opk & 0xffff, ov1, (opk >> 16) & 0xffff);
            tv0[s] = v0; tv1[s] = v1; tpk[s] = (i1 << 16) | i0;
        }
    }

    __syncthreads();
    float4* M = reinterpret_cast<float4*>(lds);   // [128][2]
    if (llo == 0) {
        #pragma unroll
        for (int i = 0; i < 4; ++i)
            #pragma unroll
            for (int r = 0; r < 4; ++r) {
                const int rowl = wr * 64 + i * 16 + lhi * 4 + r;
                const int s = i * 4 + r;
                M[rowl * 2 + wc] = make_float4(tv0[s], __int_as_float(tpk[s] & 0xffff),
                                               tv1[s], __int_as_float((tpk[s] >> 16) & 0xffff));
            }
    }
    __syncthreads();
    if (tid < 128) {
        float4 A4 = M[tid * 2 + 0], B4 = M[tid * 2 + 1];
        float v0 = A4.x, v1 = A4.z;
        int i0 = __float_as_int(A4.y), i1 = __float_as_int(A4.w);
        top2_merge(v0, i0, v1, i1, B4.x, __float_as_int(B4.y), B4.z, __float_as_int(B4.w));
        top2[(size_t)(rb * 128 + tid) * NCHUNK + chunk] =
            make_float4(v0, __int_as_float(i0), v1, __int_as_float(i1));
    }
}

// ---------- k3: fp64 rescore + gather + loss partials ----------
__global__ void rescore_kernel(const float* __restrict__ X, const float* __restrict__ E,
                               const float4* __restrict__ top2, float* __restrict__ out,
                               double* __restrict__ partials) {
    const int lane = threadIdx.x & 63;
    const int wid  = (blockIdx.x * blockDim.x + threadIdx.x) >> 6;
    const int nw   = (gridDim.x * blockDim.x) >> 6;
    double wloc = 0.0;

    for (int row = wid; row < B_N; row += nw) {
        float4 t0 = top2[(size_t)row * NCHUNK + 0];
        float4 t1 = top2[(size_t)row * NCHUNK + 1];
        int cand[4] = { __float_as_int(t0.y), __float_as_int(t0.w),
                        __float_as_int(t1.y), __float_as_int(t1.w) };
        const float4 xv = *reinterpret_cast<const float4*>(X + (size_t)row * D_N + lane * 4);

        double bestd = 1e300; int besti = 0x7fffffff;
        float4 beste = make_float4(0.f, 0.f, 0.f, 0.f);
        #pragma unroll
        for (int c = 0; c < 4; ++c) {
            const int k = cand[c];
            const float4 ev = *reinterpret_cast<const float4*>(E + (size_t)k * D_N + lane * 4);
            double dx = (double)xv.x - (double)ev.x;
            double dy = (double)xv.y - (double)ev.y;
            double dz = (double)xv.z - (double)ev.z;
            double dw = (double)xv.w - (double)ev.w;
            double s = dx * dx + dy * dy + dz * dz + dw * dw;
            #pragma unroll
            for (int o = 32; o; o >>= 1) s += __shfl_xor(s, o, 64);
            if (s < bestd || (s == bestd && k < besti)) { bestd = s; besti = k; beste = ev; }
        }
        *reinterpret_cast<float4*>(out + (size_t)row * D_N + lane * 4) = beste;
        wloc += bestd;
    }

    __shared__ double bsum[8];
    const int widx = threadIdx.x >> 6;
    if (lane == 0) bsum[widx] = wloc;
    __syncthreads();
    if (threadIdx.x == 0) {
        double s = 0.0;
        for (int w = 0; w < (int)(blockDim.x >> 6); ++w) s += bsum[w];
        partials[blockIdx.x] = s;
    }
}

__global__ void finalize_kernel(const double* __restrict__ partials, int n,
                                float* __restrict__ loss_out) {
    __shared__ double sm[256];
    double s = 0.0;
    for (int i = threadIdx.x; i < n; i += 256) s += partials[i];
    sm[threadIdx.x] = s;
    __syncthreads();
    for (int st = 128; st; st >>= 1) {
        if (threadIdx.x < st) sm[threadIdx.x] += sm[threadIdx.x + st];
        __syncthreads();
    }
    if (threadIdx.x == 0)
        *loss_out = (float)(1.25 * sm[0] / (double)((size_t)B_N * D_N));
}

extern "C" void kernel_launch(void* const* d_in, const int* in_sizes, int n_in,
                              void* d_out, int out_size, void* d_ws, size_t ws_size,
                              hipStream_t stream) {
    const float* X = (const float*)d_in[0];   // [B, D]
    const float* E = (const float*)d_in[1];   // [K, D]
    float* out = (float*)d_out;               // [B*D] quantized, then [1] loss
    char* ws = (char*)d_ws;

    u16*    Xsw      = (u16*)d_out;           // 32 MiB scratch inside d_out (overwritten by rescore)
    float4* top2     = (float4*)(ws + TOP2_OFF);
    float*  en2      = (float*)(ws + EN2_OFF);
    double* partials = (double*)(ws + PART_OFF);

    xconv_kernel<<<(B_N * 32) / 256, 256, 0, stream>>>(X, Xsw);
    en2_kernel<<<K_N / 4, 256, 0, stream>>>(E, en2);
    dist_kernel<<<dim3(B_N / 128, NCHUNK), 256, 0, stream>>>(Xsw, E, en2, top2);
    rescore_kernel<<<512, 256, 0, stream>>>(X, E, top2, out, partials);
    finalize_kernel<<<1, 256, 0, stream>>>(partials, 512, out + (size_t)B_N * D_N);
}